// Round 2
// baseline (1393.894 us; speedup 1.0000x reference)
//
#include <hip/hip_runtime.h>

typedef unsigned short u16;
typedef unsigned int u32;

#define NTOK 144
#define CDIM 192
#define NHEADS 6
#define HDIM 32
#define NWIN 64
#define NB 30
#define NBLK (NB * NWIN)
#define SCALE 0.17677669529663687f

typedef __bf16 bf16x8 __attribute__((ext_vector_type(8)));
typedef u16 u16x8 __attribute__((ext_vector_type(8)));
typedef float f32x4 __attribute__((ext_vector_type(4)));

__device__ __forceinline__ float bf2f(u16 u) {
    union { u32 i; float f; } v; v.i = ((u32)u) << 16; return v.f;
}
__device__ __forceinline__ u16 f2bf(float f) {
    union { float f; u32 i; } v; v.f = f;
    u32 r = v.i + 0x7FFFu + ((v.i >> 16) & 1u);   // RNE
    return (u16)(r >> 16);
}

// -------- dtype-robust accessors (fm==1: raw buffers are fp32) --------
__device__ __forceinline__ bf16x8 ld_frag(const void* base, size_t idx, int fm) {
    if (!fm) return *(const bf16x8*)((const u16*)base + idx);
    const float* pf = (const float*)base;
    u16x8 t;
#pragma unroll
    for (int j = 0; j < 8; ++j) t[j] = f2bf(pf[idx + j]);
    union { u16x8 u; bf16x8 b; } cv; cv.u = t; return cv.b;
}
__device__ __forceinline__ float ld_s(const void* base, size_t idx, int fm) {
    return fm ? ((const float*)base)[idx] : bf2f(((const u16*)base)[idx]);
}
__device__ __forceinline__ void st_s(void* base, size_t idx, float v, int fm) {
    if (fm) ((float*)base)[idx] = v; else ((u16*)base)[idx] = f2bf(v);
}

// ---------------- LDS layout (u16 units, total 69888 u16 = 139,776 B) ----------------
// Q [144][40] @0, K [144][40] @5760      (t1-scatter -> t2)
// P [144][168] @11520                    (Pwrite -> t3; cols 144..159 zeroed per head)
// vT [32][168] @35712                    (t1-scatter -> t3; cols 144..167 zeroed once)
// OA [144][200] @41088                   (per-head Owrite slot cols h*32.. -> final t4)
#define Q_OFF  0
#define K_OFF  5760
#define QK_STR 40
#define P_OFF  11520
#define P_STR  168
#define VT_OFF 35712
#define VT_STR 168
#define OA_OFF 41088
#define OA_STR 200
#define SM_TOT 69888

// -------- detector: bf16 vs fp32 input encoding --------
__global__ void detect_mode(const u16* __restrict__ w, int* __restrict__ flag) {
    __shared__ int cnt;
    if (threadIdx.x == 0) cnt = 0;
    __syncthreads();
    int h = 0;
    for (int i = threadIdx.x; i < 4096; i += 256) {
        int e = (w[i] >> 7) & 0xFF;
        if (e >= 0x8E) h++;
    }
    atomicAdd(&cnt, h);
    __syncthreads();
    if (threadIdx.x == 0) flag[0] = (cnt > 64) ? 1 : 0;
}

// -------- prologue: materialize bias_g[w][h][n][m] as canonical bf16 --------
__global__ void bias_gather(const void* __restrict__ table, const int* __restrict__ pos,
                            u16* __restrict__ bias_g, const int* __restrict__ mode) {
    const int fm = mode[0];
    int wh = blockIdx.x;            // 0..383
    int w = wh / NHEADS, h = wh % NHEADS;
    u16* o = bias_g + (size_t)wh * (NTOK * NTOK);
    for (int i = threadIdx.x; i < NTOK * NTOK; i += 256) {
        int idx = pos[i];
        size_t j = ((size_t)idx * NWIN + w) * NHEADS + h;
        o[i] = fm ? f2bf(((const float*)table)[j]) : ((const u16*)table)[j];
    }
}

// -------- prologue: canonical bf16 weights in workspace (one-time) --------
__global__ void wconv(const void* __restrict__ qkv_w, const void* __restrict__ qkv_b,
                      const void* __restrict__ proj_w, const void* __restrict__ proj_b,
                      u16* __restrict__ qkvw_c, u16* __restrict__ projw_c,
                      u16* __restrict__ qkvb_c, u16* __restrict__ projb_c,
                      const int* __restrict__ mode) {
    const int fm = mode[0];
    const int gid = blockIdx.x * blockDim.x + threadIdx.x;
    const int np  = gridDim.x * blockDim.x;
    const int NQW = 3 * CDIM * CDIM, NPW = CDIM * CDIM;
    if (fm) {
        const float* a = (const float*)qkv_w;
        const float* b = (const float*)proj_w;
        const float* c = (const float*)qkv_b;
        const float* d = (const float*)proj_b;
        for (int i = gid; i < NQW; i += np) qkvw_c[i] = f2bf(a[i]);
        for (int i = gid; i < NPW; i += np) projw_c[i] = f2bf(b[i]);
        for (int i = gid; i < 3 * CDIM; i += np) qkvb_c[i] = f2bf(c[i]);
        for (int i = gid; i < CDIM; i += np) projb_c[i] = f2bf(d[i]);
    } else {
        const u16* a = (const u16*)qkv_w;
        const u16* b = (const u16*)proj_w;
        const u16* c = (const u16*)qkv_b;
        const u16* d = (const u16*)proj_b;
        for (int i = gid; i < NQW; i += np) qkvw_c[i] = a[i];
        for (int i = gid; i < NPW; i += np) projw_c[i] = b[i];
        for (int i = gid; i < 3 * CDIM; i += np) qkvb_c[i] = c[i];
        for (int i = gid; i < CDIM; i += np) projb_c[i] = d[i];
    }
}

// ---------------- main fused kernel: one block per (b,w) window ----------------
// FASTW=1: weights/biases from canonical bf16 ws buffers; bias from bias_g.
// FASTW=0: generic fallback (raw weights via scalar assembly; bias per use_bias_g).
template<int FASTW>
__global__ __launch_bounds__(576, 3)
void earth_attn(const void* __restrict__ x, const void* __restrict__ qkv_w,
                const void* __restrict__ qkv_b, const void* __restrict__ proj_w,
                const void* __restrict__ proj_b, const void* __restrict__ bias_table,
                const int* __restrict__ pos_index,
                const u16* __restrict__ qkvw_c, const u16* __restrict__ projw_c,
                const u16* __restrict__ qkvb_c, const u16* __restrict__ projb_c,
                const u16* __restrict__ bias_g, int use_bias_g,
                void* __restrict__ out, const int* __restrict__ mode) {
    __shared__ __align__(16) u16 sm[SM_TOT];

    const int fm   = mode[0];
    const int tid  = threadIdx.x;
    const int wv   = tid >> 6;       // 0..8  (16-row M-tile owner)
    const int lane = tid & 63;
    const int l15  = lane & 15;
    const int lq   = lane >> 4;      // 0..3

    // XCD-chunked swizzle + window-major remap (bias_g/weights L2-local per XCD)
    const int blk   = blockIdx.x;                       // 0..1919
    const int virt  = (blk & 7) * (NBLK / 8) + (blk >> 3);
    const int w     = virt / NB;                        // 0..63
    const int bwlin = (virt % NB) * NWIN + w;           // linear (b,w) index into x/out

    // P0a: zero vT region incl. K-pad cols (written cols 0..143 each head; pad stays 0)
    {
        uint4 z; z.x = z.y = z.z = z.w = 0u;
        for (int i = tid; i < (32 * VT_STR) / 8; i += 576) *(uint4*)&sm[VT_OFF + i * 8] = z;
    }

    // P0b: x A-fragments -> registers, once per block (reused by all 6 heads)
    bf16x8 xfrag[6];
    {
        const size_t xrow = ((size_t)bwlin * NTOK + wv * 16 + l15) * CDIM;
        if (fm) {
            const float* xs = (const float*)x + xrow;
#pragma unroll
            for (int kt = 0; kt < 6; ++kt) {
                const float4 a0 = *(const float4*)(xs + kt * 32 + lq * 8);
                const float4 a1 = *(const float4*)(xs + kt * 32 + lq * 8 + 4);
                union { u16x8 u; bf16x8 b; } cv;
                cv.u[0] = f2bf(a0.x); cv.u[1] = f2bf(a0.y);
                cv.u[2] = f2bf(a0.z); cv.u[3] = f2bf(a0.w);
                cv.u[4] = f2bf(a1.x); cv.u[5] = f2bf(a1.y);
                cv.u[6] = f2bf(a1.z); cv.u[7] = f2bf(a1.w);
                xfrag[kt] = cv.b;
            }
        } else {
            const u16* xs = (const u16*)x + xrow;
#pragma unroll
            for (int kt = 0; kt < 6; ++kt)
                xfrag[kt] = *(const bf16x8*)(xs + kt * 32 + lq * 8);
        }
    }
    __syncthreads();                                  // B0 (vT pad visible)

    const f32x4 fzero = {0.f, 0.f, 0.f, 0.f};

    for (int h = 0; h < NHEADS; ++h) {
        const int hoff = h * HDIM;

        // ---- bias prefetch (global, independent of LDS; overlaps t1 loads) ----
        float bsv[9][4];
        if (FASTW || use_bias_g) {
            const u16* bg = bias_g + (size_t)(w * NHEADS + h) * (NTOK * NTOK);
#pragma unroll
            for (int nt = 0; nt < 9; ++nt) {
                int col = nt * 16 + l15;
#pragma unroll
                for (int r = 0; r < 4; ++r)
                    bsv[nt][r] = bf2f(bg[(wv * 16 + lq * 4 + r) * NTOK + col]);
            }
        } else {
#pragma unroll
            for (int nt = 0; nt < 9; ++nt) {
                int col = nt * 16 + l15;
#pragma unroll
                for (int r = 0; r < 4; ++r) {
                    int idx = pos_index[(wv * 16 + lq * 4 + r) * NTOK + col];
                    bsv[nt][r] = ld_s(bias_table, ((size_t)idx * NWIN + w) * NHEADS + h, fm);
                }
            }
        }

        // ---- t1: qkv_h = x @ Wh^T (M=144,N=96,K=192); A in regs, B from global L2 ----
        {
            f32x4 acc[6];
            for (int nt = 0; nt < 6; ++nt) acc[nt] = fzero;
            int wrow[6];
#pragma unroll
            for (int nt = 0; nt < 6; ++nt) {
                int c = nt * 16 + l15, s = c >> 5, d = c & 31;
                wrow[nt] = (s * CDIM + hoff + d) * CDIM;
            }
#pragma unroll
            for (int kt = 0; kt < 6; ++kt) {
#pragma unroll
                for (int nt = 0; nt < 6; ++nt) {
                    bf16x8 bb = FASTW
                        ? *(const bf16x8*)&qkvw_c[(size_t)wrow[nt] + kt * 32 + lq * 8]
                        : ld_frag(qkv_w, (size_t)wrow[nt] + kt * 32 + lq * 8, fm);
                    acc[nt] = __builtin_amdgcn_mfma_f32_16x16x32_bf16(xfrag[kt], bb, acc[nt], 0, 0, 0);
                }
            }
            // scatter q (scaled) / k / v^T as bf16
#pragma unroll
            for (int nt = 0; nt < 6; ++nt) {
                int col = nt * 16 + l15;         // 0..95
                int s = col >> 5, d = col & 31;
                float bias = FASTW ? bf2f(qkvb_c[s * CDIM + hoff + d])
                                   : ld_s(qkv_b, s * CDIM + hoff + d, fm);
#pragma unroll
                for (int r = 0; r < 4; ++r) {
                    int row = wv * 16 + lq * 4 + r;
                    float v = acc[nt][r] + bias;
                    if (s == 0)      sm[Q_OFF + row * QK_STR + d] = f2bf(v * SCALE);
                    else if (s == 1) sm[K_OFF + row * QK_STR + d] = f2bf(v);
                    else             sm[VT_OFF + d * VT_STR + row] = f2bf(v);
                }
            }
        }
        __syncthreads();                              // B1 (q/k/vT visible)

        // ---- t2: S = q @ k^T + bias; softmax (registers) ----
        f32x4 sacc[9];
        {
            bf16x8 a = *(const bf16x8*)&sm[Q_OFF + (wv * 16 + l15) * QK_STR + lq * 8];
#pragma unroll
            for (int nt = 0; nt < 9; ++nt) {
                bf16x8 bb = *(const bf16x8*)&sm[K_OFF + (nt * 16 + l15) * QK_STR + lq * 8];
                sacc[nt] = __builtin_amdgcn_mfma_f32_16x16x32_bf16(a, bb, fzero, 0, 0, 0);
            }
#pragma unroll
            for (int nt = 0; nt < 9; ++nt)
#pragma unroll
                for (int r = 0; r < 4; ++r) sacc[nt][r] += bsv[nt][r];
#pragma unroll
            for (int r = 0; r < 4; ++r) {
                float m = -1e30f;
                for (int nt = 0; nt < 9; ++nt) m = fmaxf(m, sacc[nt][r]);
                for (int d = 1; d < 16; d <<= 1) m = fmaxf(m, __shfl_xor(m, d, 64));
                float s = 0.f;
                for (int nt = 0; nt < 9; ++nt) {
                    float e = __expf(sacc[nt][r] - m);
                    sacc[nt][r] = e; s += e;
                }
                for (int d = 1; d < 16; d <<= 1) s += __shfl_xor(s, d, 64);
                float inv = 1.0f / s;
                for (int nt = 0; nt < 9; ++nt) sacc[nt][r] *= inv;
            }
        }

        // ---- P write: own region (no barrier needed before; prev reader fenced at B4) ----
#pragma unroll
        for (int r = 0; r < 4; ++r) {
            int row = wv * 16 + lq * 4 + r;
#pragma unroll
            for (int nt = 0; nt < 9; ++nt)
                sm[P_OFF + row * P_STR + nt * 16 + l15] = f2bf(sacc[nt][r]);
            sm[P_OFF + row * P_STR + 144 + l15] = 0;   // K-pad cols 144..159
        }
        __syncthreads();                              // B3 (P/vT ready for t3)

        // ---- t3: O_h = P @ v  (M=144, N=32, K=160 padded) ----
        f32x4 pv[2] = {fzero, fzero};
#pragma unroll
        for (int kt = 0; kt < 5; ++kt) {
            bf16x8 a = *(const bf16x8*)&sm[P_OFF + (wv * 16 + l15) * P_STR + kt * 32 + lq * 8];
#pragma unroll
            for (int dt = 0; dt < 2; ++dt) {
                bf16x8 bb = *(const bf16x8*)&sm[VT_OFF + (dt * 16 + l15) * VT_STR + kt * 32 + lq * 8];
                pv[dt] = __builtin_amdgcn_mfma_f32_16x16x32_bf16(a, bb, pv[dt], 0, 0, 0);
            }
        }

        // ---- O write into persistent OA slot (cols h*32..h*32+31) ----
#pragma unroll
        for (int dt = 0; dt < 2; ++dt)
#pragma unroll
            for (int r = 0; r < 4; ++r) {
                int row = wv * 16 + lq * 4 + r;
                sm[OA_OFF + row * OA_STR + hoff + dt * 16 + l15] = f2bf(pv[dt][r]);
            }
        __syncthreads();                              // B4 (t3 reads done; next scatter safe)
    }

    // ---- t4 (once): out = OA @ proj_w^T  (M=144, N=192, K=192) ----
    f32x4 oacc[12];
    for (int nt = 0; nt < 12; ++nt) oacc[nt] = fzero;
    {
        bf16x8 a[6];
#pragma unroll
        for (int kt = 0; kt < 6; ++kt)
            a[kt] = *(const bf16x8*)&sm[OA_OFF + (wv * 16 + l15) * OA_STR + kt * 32 + lq * 8];
#pragma unroll
        for (int kt = 0; kt < 6; ++kt) {
#pragma unroll
            for (int nt = 0; nt < 12; ++nt) {
                bf16x8 bb = FASTW
                    ? *(const bf16x8*)&projw_c[(size_t)(nt * 16 + l15) * CDIM + kt * 32 + lq * 8]
                    : ld_frag(proj_w, (size_t)(nt * 16 + l15) * CDIM + kt * 32 + lq * 8, fm);
                oacc[nt] = __builtin_amdgcn_mfma_f32_16x16x32_bf16(a[kt], bb, oacc[nt], 0, 0, 0);
            }
        }
    }

    // ---- epilogue: + proj_b, store (dtype per mode) ----
    const size_t obase = (size_t)bwlin * (NTOK * CDIM);
#pragma unroll
    for (int nt = 0; nt < 12; ++nt) {
        int col = nt * 16 + l15;
        float pb = FASTW ? bf2f(projb_c[col]) : ld_s(proj_b, col, fm);
#pragma unroll
        for (int r = 0; r < 4; ++r) {
            int row = wv * 16 + lq * 4 + r;
            st_s(out, obase + row * CDIM + col, oacc[nt][r] + pb, fm);
        }
    }
}

extern "C" void kernel_launch(void* const* d_in, const int* in_sizes, int n_in,
                              void* d_out, int out_size, void* d_ws, size_t ws_size,
                              hipStream_t stream) {
    const void* x          = d_in[0];
    const void* qkv_w      = d_in[1];
    const void* qkv_b      = d_in[2];
    const void* proj_w     = d_in[3];
    const void* proj_b     = d_in[4];
    const void* bias_table = d_in[5];
    const int*  pos_index  = (const int*)d_in[6];

    // ---- workspace layout: [16B flag][bias_g 15.93MB][qkvw 216KB][projw 72KB][qkvb][projb]
    int*  mode_flag = (int*)d_ws;
    char* p         = (char*)d_ws + 16;
    const size_t biasg_bytes = (size_t)NWIN * NHEADS * NTOK * NTOK * sizeof(u16);
    u16* bias_g = (u16*)p;            p += biasg_bytes;
    const size_t qkvw_bytes = (size_t)3 * CDIM * CDIM * sizeof(u16);
    const size_t projw_bytes = (size_t)CDIM * CDIM * sizeof(u16);
    u16* qkvw_c = (u16*)p;            p += qkvw_bytes;
    u16* projw_c = (u16*)p;           p += projw_bytes;
    u16* qkvb_c = (u16*)p;            p += 3 * CDIM * sizeof(u16);
    u16* projb_c = (u16*)p;           p += CDIM * sizeof(u16);
    const size_t need_biasg = 16 + biasg_bytes;
    const size_t need_full  = (size_t)(p - (char*)d_ws);

    int use_bias_g = (ws_size >= need_biasg) ? 1 : 0;
    int use_full   = (ws_size >= need_full) ? 1 : 0;

    detect_mode<<<dim3(1), dim3(256), 0, stream>>>((const u16*)qkv_w, mode_flag);
    if (use_bias_g)
        bias_gather<<<dim3(NWIN * NHEADS), dim3(256), 0, stream>>>(
            bias_table, pos_index, bias_g, mode_flag);
    if (use_full) {
        wconv<<<dim3(192), dim3(256), 0, stream>>>(
            qkv_w, qkv_b, proj_w, proj_b, qkvw_c, projw_c, qkvb_c, projb_c, mode_flag);
        earth_attn<1><<<dim3(NBLK), dim3(576), 0, stream>>>(
            x, qkv_w, qkv_b, proj_w, proj_b, bias_table, pos_index,
            qkvw_c, projw_c, qkvb_c, projb_c, bias_g, 1, d_out, mode_flag);
    } else {
        earth_attn<0><<<dim3(NBLK), dim3(576), 0, stream>>>(
            x, qkv_w, qkv_b, proj_w, proj_b, bias_table, pos_index,
            qkvw_c, projw_c, qkvb_c, projb_c, bias_g, use_bias_g, d_out, mode_flag);
    }
}